// Round 1
// baseline (1402.842 us; speedup 1.0000x reference)
//
#include <hip/hip_runtime.h>

#define N_NODES 50000
#define N_EDGES 800000

typedef __attribute__((ext_vector_type(8))) short bf16x8;
typedef __attribute__((ext_vector_type(4))) float f32x4;
typedef __attribute__((ext_vector_type(2))) float f32x2;

__device__ __forceinline__ float bf2f(unsigned short u) {
  union { unsigned int u; float f; } c; c.u = ((unsigned int)u) << 16; return c.f;
}
__device__ __forceinline__ unsigned short f2bf(float f) {
  union { float f; unsigned int u; } c; c.f = f;
  unsigned int r = c.u + 0x7FFFu + ((c.u >> 16) & 1u);  // RNE
  return (unsigned short)(r >> 16);
}
__device__ __forceinline__ float sspf(float x) {
  // softplus(x) - log(2)
  return fmaxf(x, 0.0f) + __logf(1.0f + __expf(-fabsf(x))) - 0.69314718055994531f;
}
__device__ __forceinline__ f32x4 MFMA(bf16x8 a, bf16x8 b, f32x4 c) {
  return __builtin_amdgcn_mfma_f32_16x16x32_bf16(a, b, c, 0, 0, 0);
}
__device__ __forceinline__ f32x4 f4zero() { f32x4 z = {0.f, 0.f, 0.f, 0.f}; return z; }

// convert 8 contiguous f32 (16B-aligned) to bf16x8
__device__ __forceinline__ bf16x8 cvt8(const float* __restrict__ p) {
  f32x4 x0 = *(const f32x4*)p;
  f32x4 x1 = *(const f32x4*)(p + 4);
  bf16x8 t;
  t[0] = (short)f2bf(x0[0]); t[1] = (short)f2bf(x0[1]);
  t[2] = (short)f2bf(x0[2]); t[3] = (short)f2bf(x0[3]);
  t[4] = (short)f2bf(x1[0]); t[5] = (short)f2bf(x1[1]);
  t[6] = (short)f2bf(x1[2]); t[7] = (short)f2bf(x1[3]);
  return t;
}

// ---------------------------------------------------------------------------
// Generic GEMM: Out[M,256] = act(A[M,256] @ W[256,256] + bias)
// Wt is W transposed: Wt[col][k] (bf16). ADT: 0=A bf16, 1=A f32.
// ACT: 0=none, 1=ShiftedSoftplus. ODT: 0=Out bf16, 1=Out f32.
// Block = 256 thr (4 waves), computes 64 rows x 256 cols. Wave w owns cols
// [64w,64w+64). MFMA 16x16x32 bf16; k map = 8*(l>>4)+j for both A and B
// (consistency => correct for any HW k-permutation); C/D: col=l&15,
// row=4*(l>>4)+i (m89-verified).
// ---------------------------------------------------------------------------
template<int ADT, int ACT, int ODT>
__global__ __launch_bounds__(256) void gemm_k256(
    const void* __restrict__ Av, const unsigned short* __restrict__ Wt,
    const float* __restrict__ bias, void* __restrict__ Outv, int M)
{
  const int m0  = (int)blockIdx.x * 64;
  const int tid = (int)threadIdx.x;
  const int w   = tid >> 6;
  const int l   = tid & 63;
  const int lr  = l & 15;
  const int g   = l >> 4;

  f32x4 acc[4][4];
#pragma unroll
  for (int a = 0; a < 4; ++a)
#pragma unroll
    for (int b = 0; b < 4; ++b) acc[a][b] = f4zero();

#pragma unroll
  for (int ks = 0; ks < 8; ++ks) {
    const int kb = ks * 32 + g * 8;
    bf16x8 af[4], bfr[4];
#pragma unroll
    for (int mf = 0; mf < 4; ++mf) {
      int row = m0 + mf * 16 + lr;
      if (row >= M) row = M - 1;   // clamp (last block only); stores are guarded
      if (ADT == 0)
        af[mf] = *(const bf16x8*)((const unsigned short*)Av + (size_t)row * 256 + kb);
      else
        af[mf] = cvt8((const float*)Av + (size_t)row * 256 + kb);
    }
#pragma unroll
    for (int nf = 0; nf < 4; ++nf) {
      const int col = w * 64 + nf * 16 + lr;
      bfr[nf] = *(const bf16x8*)(Wt + (size_t)col * 256 + kb);
    }
#pragma unroll
    for (int mf = 0; mf < 4; ++mf)
#pragma unroll
      for (int nf = 0; nf < 4; ++nf)
        acc[mf][nf] = MFMA(af[mf], bfr[nf], acc[mf][nf]);
  }

#pragma unroll
  for (int nf = 0; nf < 4; ++nf) {
    const int col = w * 64 + nf * 16 + lr;
    const float bs = bias[col];
#pragma unroll
    for (int mf = 0; mf < 4; ++mf) {
#pragma unroll
      for (int i = 0; i < 4; ++i) {
        const int row = m0 + mf * 16 + g * 4 + i;
        if (row < M) {
          float x = acc[mf][nf][i] + bs;
          if (ACT) x = sspf(x);
          if (ODT == 0)
            ((unsigned short*)Outv)[(size_t)row * 256 + col] = f2bf(x);
          else
            ((float*)Outv)[(size_t)row * 256 + col] = x;
        }
      }
    }
  }
}

// ---------------------------------------------------------------------------
// Fused edge pipeline, 64 edges per block:
//   t  = ssp(edge_attr[64,50] @ m1 + b1)         (MFMA, K padded to 64)
//   Wf = ssp(t @ m2 + b2) * cutoff(edge_weight)  (MFMA, t via swizzled LDS)
//   agg[dst] += h1[src] * Wf                     (gather + f32 atomics)
// Avoids materializing t/Wf in HBM (saves ~1.6 GB traffic).
// ---------------------------------------------------------------------------
__global__ __launch_bounds__(256) void edge_fused(
    const float* __restrict__ eattr, const float* __restrict__ ew,
    const int* __restrict__ eidx,
    const unsigned short* __restrict__ m1t, const float* __restrict__ m1b,
    const unsigned short* __restrict__ m2t, const float* __restrict__ m2b,
    const unsigned short* __restrict__ h1, float* __restrict__ agg)
{
  __shared__ unsigned short t_lds[64 * 256];  // 32 KiB, XOR-swizzled
  __shared__ float Cs[64];
  __shared__ int s_src[64], s_dst[64];

  const int e0  = (int)blockIdx.x * 64;
  const int tid = (int)threadIdx.x;
  if (tid < 64) {
    const int e = e0 + tid;
    Cs[tid]    = 0.5f * (__cosf(ew[e] * 0.31415926535897931f) + 1.0f);
    s_src[tid] = eidx[e];
    s_dst[tid] = eidx[N_EDGES + e];
  }

  const int w = tid >> 6, l = tid & 63, lr = l & 15, g = l >> 4;

  f32x4 acc[4][4];
#pragma unroll
  for (int a = 0; a < 4; ++a)
#pragma unroll
    for (int b = 0; b < 4; ++b) acc[a][b] = f4zero();

  // ---- stage 1: K=50 (padded to 64; m1t zero-padded kills k>=50 lanes)
#pragma unroll
  for (int ks = 0; ks < 2; ++ks) {
    const int kb = ks * 32 + g * 8;
    bf16x8 af[4], bfr[4];
#pragma unroll
    for (int mf = 0; mf < 4; ++mf) {
      const int row = e0 + mf * 16 + lr;                 // always < E (E%64==0)
      const float* ap = eattr + (size_t)row * 50 + kb;
      bf16x8 t;
      if (kb + 8 <= 50) {                                // fully in-row, 8B-aligned
        f32x2 x0 = *(const f32x2*)(ap);
        f32x2 x1 = *(const f32x2*)(ap + 2);
        f32x2 x2 = *(const f32x2*)(ap + 4);
        f32x2 x3 = *(const f32x2*)(ap + 6);
        t[0] = (short)f2bf(x0[0]); t[1] = (short)f2bf(x0[1]);
        t[2] = (short)f2bf(x1[0]); t[3] = (short)f2bf(x1[1]);
        t[4] = (short)f2bf(x2[0]); t[5] = (short)f2bf(x2[1]);
        t[6] = (short)f2bf(x3[0]); t[7] = (short)f2bf(x3[1]);
      } else {                                           // kb=48 (2 valid) / kb=56 (none)
#pragma unroll
        for (int j = 0; j < 8; ++j)
          t[j] = (kb + j < 50) ? (short)f2bf(ap[j]) : (short)0;
      }
      af[mf] = t;
    }
#pragma unroll
    for (int nf = 0; nf < 4; ++nf) {
      const int col = w * 64 + nf * 16 + lr;
      bfr[nf] = *(const bf16x8*)(m1t + col * 64 + kb);
    }
#pragma unroll
    for (int mf = 0; mf < 4; ++mf)
#pragma unroll
      for (int nf = 0; nf < 4; ++nf)
        acc[mf][nf] = MFMA(af[mf], bfr[nf], acc[mf][nf]);
  }

  // ---- epilogue 1: ssp -> t_lds (bf16, byte ^= (row&7)<<4 swizzle)
#pragma unroll
  for (int nf = 0; nf < 4; ++nf) {
    const int col = w * 64 + nf * 16 + lr;
    const float bs = m1b[col];
#pragma unroll
    for (int mf = 0; mf < 4; ++mf)
#pragma unroll
      for (int i = 0; i < 4; ++i) {
        const int r = mf * 16 + g * 4 + i;
        const float x = sspf(acc[mf][nf][i] + bs);
        const int byt = (r * 512 + col * 2) ^ ((r & 7) << 4);
        *(unsigned short*)((char*)t_lds + byt) = f2bf(x);
      }
  }
  __syncthreads();

  // ---- stage 2: K=256
#pragma unroll
  for (int a = 0; a < 4; ++a)
#pragma unroll
    for (int b = 0; b < 4; ++b) acc[a][b] = f4zero();

#pragma unroll
  for (int ks = 0; ks < 8; ++ks) {
    const int kb = ks * 32 + g * 8;
    bf16x8 af[4], bfr[4];
#pragma unroll
    for (int mf = 0; mf < 4; ++mf) {
      const int r = mf * 16 + lr;
      const int byt = (r * 512 + kb * 2) ^ ((r & 7) << 4);
      af[mf] = *(const bf16x8*)((const char*)t_lds + byt);
    }
#pragma unroll
    for (int nf = 0; nf < 4; ++nf) {
      const int col = w * 64 + nf * 16 + lr;
      bfr[nf] = *(const bf16x8*)(m2t + (size_t)col * 256 + kb);
    }
#pragma unroll
    for (int mf = 0; mf < 4; ++mf)
#pragma unroll
      for (int nf = 0; nf < 4; ++nf)
        acc[mf][nf] = MFMA(af[mf], bfr[nf], acc[mf][nf]);
  }

  // ---- epilogue 2: Wf = ssp(acc+b2)*C; agg[dst] += h1[src]*Wf
#pragma unroll
  for (int nf = 0; nf < 4; ++nf) {
    const int col = w * 64 + nf * 16 + lr;
    const float bs = m2b[col];
#pragma unroll
    for (int mf = 0; mf < 4; ++mf) {
#pragma unroll
      for (int i = 0; i < 4; ++i) {
        const int er = mf * 16 + g * 4 + i;
        const float wf = sspf(acc[mf][nf][i] + bs) * Cs[er];
        const float xj = bf2f(h1[(size_t)s_src[er] * 256 + col]);
        __hip_atomic_fetch_add(agg + (size_t)s_dst[er] * 256 + col, xj * wf,
                               __ATOMIC_RELAXED, __HIP_MEMORY_SCOPE_AGENT);
      }
    }
  }
}

// ---------------------------------------------------------------------------
// Transpose + downcast weights: Wt[col][k] bf16. m1 padded K 50->64 w/ zeros.
// ---------------------------------------------------------------------------
__global__ __launch_bounds__(256) void prep_weights(
    const float* __restrict__ aw, const float* __restrict__ m1,
    const float* __restrict__ m2, const float* __restrict__ o1,
    const float* __restrict__ o2,
    unsigned short* __restrict__ awt, unsigned short* __restrict__ m1t,
    unsigned short* __restrict__ m2t, unsigned short* __restrict__ o1t,
    unsigned short* __restrict__ o2t)
{
  const int i = (int)blockIdx.x * 256 + (int)threadIdx.x;  // 0..65535
  const int c = i >> 8, k = i & 255;
  const int src = k * 256 + c;
  awt[i] = f2bf(aw[src]);
  m2t[i] = f2bf(m2[src]);
  o1t[i] = f2bf(o1[src]);
  o2t[i] = f2bf(o2[src]);
  if (k < 64) m1t[c * 64 + k] = (k < 50) ? f2bf(m1[k * 256 + c]) : (unsigned short)0;
}

extern "C" void kernel_launch(void* const* d_in, const int* in_sizes, int n_in,
                              void* d_out, int out_size, void* d_ws, size_t ws_size,
                              hipStream_t stream)
{
  const float* h    = (const float*)d_in[0];
  const int*   eidx = (const int*)d_in[1];
  const float* ew   = (const float*)d_in[2];
  const float* ea   = (const float*)d_in[3];
  const float* awW  = (const float*)d_in[4];
  const float* awb  = (const float*)d_in[5];
  const float* m1W  = (const float*)d_in[6];
  const float* m1b  = (const float*)d_in[7];
  const float* m2W  = (const float*)d_in[8];
  const float* m2b  = (const float*)d_in[9];
  const float* o1W  = (const float*)d_in[10];
  const float* o1b  = (const float*)d_in[11];
  const float* o2W  = (const float*)d_in[12];
  const float* o2b  = (const float*)d_in[13];

  // ws layout (77.4 MB total):
  //   [0, 25.6MB)        h1 bf16 [N,256]   (reused for 'o' after edge_fused)
  //   [25.6MB, 76.8MB)   agg f32 [N,256]
  //   [76.8MB, ...)      transposed bf16 weights
  char* ws = (char*)d_ws;
  unsigned short* h1  = (unsigned short*)ws;
  float*          agg = (float*)(ws + 25600000);
  char* wbase = ws + 25600000 + 51200000;
  unsigned short* awt = (unsigned short*)wbase;
  unsigned short* m2t = awt + 65536;
  unsigned short* o1t = m2t + 65536;
  unsigned short* o2t = o1t + 65536;
  unsigned short* m1t = o2t + 65536;  // [256][64]

  hipMemsetAsync(agg, 0, (size_t)N_NODES * 256 * 4, stream);
  prep_weights<<<256, 256, 0, stream>>>(awW, m1W, m2W, o1W, o2W,
                                        awt, m1t, m2t, o1t, o2t);
  // h1 = h @ aw_W + aw_b
  gemm_k256<1, 0, 0><<<(N_NODES + 63) / 64, 256, 0, stream>>>(h, awt, awb, h1, N_NODES);
  // edge MLP + CFConv scatter
  edge_fused<<<N_EDGES / 64, 256, 0, stream>>>(ea, ew, eidx, m1t, m1b, m2t, m2b, h1, agg);
  // o = ssp(agg @ o1_W + o1_b)   (into h1's buffer)
  gemm_k256<1, 1, 0><<<(N_NODES + 63) / 64, 256, 0, stream>>>(agg, o1t, o1b, h1, N_NODES);
  // out = o @ o2_W + o2_b
  gemm_k256<0, 0, 1><<<(N_NODES + 63) / 64, 256, 0, stream>>>(h1, o2t, o2b, d_out, N_NODES);
}

// Round 2
// 1394.494 us; speedup vs baseline: 1.0060x; 1.0060x over previous
//
#include <hip/hip_runtime.h>

#define N_NODES 50000
#define N_EDGES 800000

typedef __attribute__((ext_vector_type(8))) short bf16x8;
typedef __attribute__((ext_vector_type(4))) float f32x4;
typedef __attribute__((ext_vector_type(2))) float f32x2;

__device__ __forceinline__ float bf2f(unsigned short u) {
  union { unsigned int u; float f; } c; c.u = ((unsigned int)u) << 16; return c.f;
}
__device__ __forceinline__ unsigned short f2bf(float f) {
  union { float f; unsigned int u; } c; c.f = f;
  unsigned int r = c.u + 0x7FFFu + ((c.u >> 16) & 1u);  // RNE
  return (unsigned short)(r >> 16);
}
__device__ __forceinline__ float sspf(float x) {
  return fmaxf(x, 0.0f) + __logf(1.0f + __expf(-fabsf(x))) - 0.69314718055994531f;
}
__device__ __forceinline__ f32x4 MFMA(bf16x8 a, bf16x8 b, f32x4 c) {
  return __builtin_amdgcn_mfma_f32_16x16x32_bf16(a, b, c, 0, 0, 0);
}
__device__ __forceinline__ f32x4 f4zero() { f32x4 z = {0.f, 0.f, 0.f, 0.f}; return z; }

__device__ __forceinline__ bf16x8 cvt8(const float* __restrict__ p) {
  f32x4 x0 = *(const f32x4*)p;
  f32x4 x1 = *(const f32x4*)(p + 4);
  bf16x8 t;
  t[0] = (short)f2bf(x0[0]); t[1] = (short)f2bf(x0[1]);
  t[2] = (short)f2bf(x0[2]); t[3] = (short)f2bf(x0[3]);
  t[4] = (short)f2bf(x1[0]); t[5] = (short)f2bf(x1[1]);
  t[6] = (short)f2bf(x1[2]); t[7] = (short)f2bf(x1[3]);
  return t;
}

// ---------------------------------------------------------------------------
// Generic GEMM: Out[M,256] = act(A[M,256] @ W[256,256] + bias)   (unchanged)
// ---------------------------------------------------------------------------
template<int ADT, int ACT, int ODT>
__global__ __launch_bounds__(256) void gemm_k256(
    const void* __restrict__ Av, const unsigned short* __restrict__ Wt,
    const float* __restrict__ bias, void* __restrict__ Outv, int M)
{
  const int m0  = (int)blockIdx.x * 64;
  const int tid = (int)threadIdx.x;
  const int w   = tid >> 6;
  const int l   = tid & 63;
  const int lr  = l & 15;
  const int g   = l >> 4;

  f32x4 acc[4][4];
#pragma unroll
  for (int a = 0; a < 4; ++a)
#pragma unroll
    for (int b = 0; b < 4; ++b) acc[a][b] = f4zero();

#pragma unroll
  for (int ks = 0; ks < 8; ++ks) {
    const int kb = ks * 32 + g * 8;
    bf16x8 af[4], bfr[4];
#pragma unroll
    for (int mf = 0; mf < 4; ++mf) {
      int row = m0 + mf * 16 + lr;
      if (row >= M) row = M - 1;
      if (ADT == 0)
        af[mf] = *(const bf16x8*)((const unsigned short*)Av + (size_t)row * 256 + kb);
      else
        af[mf] = cvt8((const float*)Av + (size_t)row * 256 + kb);
    }
#pragma unroll
    for (int nf = 0; nf < 4; ++nf) {
      const int col = w * 64 + nf * 16 + lr;
      bfr[nf] = *(const bf16x8*)(Wt + (size_t)col * 256 + kb);
    }
#pragma unroll
    for (int mf = 0; mf < 4; ++mf)
#pragma unroll
      for (int nf = 0; nf < 4; ++nf)
        acc[mf][nf] = MFMA(af[mf], bfr[nf], acc[mf][nf]);
  }

#pragma unroll
  for (int nf = 0; nf < 4; ++nf) {
    const int col = w * 64 + nf * 16 + lr;
    const float bs = bias[col];
#pragma unroll
    for (int mf = 0; mf < 4; ++mf) {
#pragma unroll
      for (int i = 0; i < 4; ++i) {
        const int row = m0 + mf * 16 + g * 4 + i;
        if (row < M) {
          float x = acc[mf][nf][i] + bs;
          if (ACT) x = sspf(x);
          if (ODT == 0)
            ((unsigned short*)Outv)[(size_t)row * 256 + col] = f2bf(x);
          else
            ((float*)Outv)[(size_t)row * 256 + col] = x;
        }
      }
    }
  }
}

// ---------------------------------------------------------------------------
// Counting sort of edges by dst: histogram -> exclusive scan -> scatter.
// Order within a dst bucket is atomic-race-determined; only affects f32
// summation order (~1e-6), far below tolerance.
// ---------------------------------------------------------------------------
__global__ __launch_bounds__(256) void hist_dst(const int* __restrict__ eidx,
                                                int* __restrict__ cnt)
{
  const int e = (int)blockIdx.x * 256 + (int)threadIdx.x;  // grid exactly E
  atomicAdd(&cnt[eidx[N_EDGES + e]], 1);
}

__global__ __launch_bounds__(1024) void scan_cnt(const int* __restrict__ cnt,
                                                 int* __restrict__ cursor)
{
  __shared__ int part[1024];
  const int t = (int)threadIdx.x;
  const int base = t * 49;                      // 1024*49 = 50176 >= 50000
  int s = 0;
#pragma unroll 7
  for (int j = 0; j < 49; ++j) {
    const int idx = base + j;
    if (idx < N_NODES) s += cnt[idx];
  }
  part[t] = s;
  __syncthreads();
  for (int off = 1; off < 1024; off <<= 1) {
    int v = 0;
    if (t >= off) v = part[t - off];
    __syncthreads();
    part[t] += v;
    __syncthreads();
  }
  int run = (t == 0) ? 0 : part[t - 1];         // exclusive prefix
#pragma unroll 7
  for (int j = 0; j < 49; ++j) {
    const int idx = base + j;
    if (idx < N_NODES) { cursor[idx] = run; run += cnt[idx]; }
  }
}

__global__ __launch_bounds__(256) void scatter_perm(const int* __restrict__ eidx,
                                                    int* __restrict__ cursor,
                                                    int* __restrict__ perm)
{
  const int e = (int)blockIdx.x * 256 + (int)threadIdx.x;
  const int d = eidx[N_EDGES + e];
  const int pos = atomicAdd(&cursor[d], 1);
  perm[pos] = e;
}

// ---------------------------------------------------------------------------
// Fused edge pipeline over dst-SORTED edges, 64 per block:
//   t  = ssp(edge_attr[perm] @ m1 + b1)     (MFMA, K padded to 64)
//   Wf = ssp(t @ m2 + b2) * cutoff(ew)      (MFMA via swizzled LDS)
//   msg = h1[src]*Wf -> LDS (bf16)          (reuse t_lds)
//   per-column segmented reduce over 64 sorted rows -> ~5 atomics/col
// Atomics: 205M -> ~16M.
// ---------------------------------------------------------------------------
__global__ __launch_bounds__(256) void edge_fused(
    const float* __restrict__ eattr, const float* __restrict__ ew,
    const int* __restrict__ eidx, const int* __restrict__ perm,
    const unsigned short* __restrict__ m1t, const float* __restrict__ m1b,
    const unsigned short* __restrict__ m2t, const float* __restrict__ m2b,
    const unsigned short* __restrict__ h1, float* __restrict__ agg)
{
  __shared__ unsigned short t_lds[64 * 256];  // 32 KiB; t, then msg
  __shared__ float Cs[64];
  __shared__ int s_src[64], s_dst[64], s_perm[64];

  const int e0  = (int)blockIdx.x * 64;
  const int tid = (int)threadIdx.x;
  if (tid < 64) {
    const int p = perm[e0 + tid];
    s_perm[tid] = p;
    Cs[tid]     = 0.5f * (__cosf(ew[p] * 0.31415926535897931f) + 1.0f);
    s_src[tid]  = eidx[p];
    s_dst[tid]  = eidx[N_EDGES + p];
  }
  __syncthreads();

  const int w = tid >> 6, l = tid & 63, lr = l & 15, g = l >> 4;

  f32x4 acc[4][4];
#pragma unroll
  for (int a = 0; a < 4; ++a)
#pragma unroll
    for (int b = 0; b < 4; ++b) acc[a][b] = f4zero();

  // ---- stage 1: K=50 (padded to 64; m1t zero-padded kills k>=50 lanes)
#pragma unroll
  for (int ks = 0; ks < 2; ++ks) {
    const int kb = ks * 32 + g * 8;
    bf16x8 af[4], bfr[4];
#pragma unroll
    for (int mf = 0; mf < 4; ++mf) {
      const int pr = s_perm[mf * 16 + lr];
      const float* ap = eattr + (size_t)pr * 50 + kb;   // pr*200B: 8B-aligned
      bf16x8 t;
      if (kb + 8 <= 50) {
        f32x2 x0 = *(const f32x2*)(ap);
        f32x2 x1 = *(const f32x2*)(ap + 2);
        f32x2 x2 = *(const f32x2*)(ap + 4);
        f32x2 x3 = *(const f32x2*)(ap + 6);
        t[0] = (short)f2bf(x0[0]); t[1] = (short)f2bf(x0[1]);
        t[2] = (short)f2bf(x1[0]); t[3] = (short)f2bf(x1[1]);
        t[4] = (short)f2bf(x2[0]); t[5] = (short)f2bf(x2[1]);
        t[6] = (short)f2bf(x3[0]); t[7] = (short)f2bf(x3[1]);
      } else {
#pragma unroll
        for (int j = 0; j < 8; ++j)
          t[j] = (kb + j < 50) ? (short)f2bf(ap[j]) : (short)0;
      }
      af[mf] = t;
    }
#pragma unroll
    for (int nf = 0; nf < 4; ++nf) {
      const int col = w * 64 + nf * 16 + lr;
      bfr[nf] = *(const bf16x8*)(m1t + col * 64 + kb);
    }
#pragma unroll
    for (int mf = 0; mf < 4; ++mf)
#pragma unroll
      for (int nf = 0; nf < 4; ++nf)
        acc[mf][nf] = MFMA(af[mf], bfr[nf], acc[mf][nf]);
  }

  // ---- epilogue 1: ssp -> t_lds (bf16, byte ^= (row&7)<<4 swizzle)
#pragma unroll
  for (int nf = 0; nf < 4; ++nf) {
    const int col = w * 64 + nf * 16 + lr;
    const float bs = m1b[col];
#pragma unroll
    for (int mf = 0; mf < 4; ++mf)
#pragma unroll
      for (int i = 0; i < 4; ++i) {
        const int r = mf * 16 + g * 4 + i;
        const float x = sspf(acc[mf][nf][i] + bs);
        const int byt = (r * 512 + col * 2) ^ ((r & 7) << 4);
        *(unsigned short*)((char*)t_lds + byt) = f2bf(x);
      }
  }
  __syncthreads();

  // ---- stage 2: K=256
#pragma unroll
  for (int a = 0; a < 4; ++a)
#pragma unroll
    for (int b = 0; b < 4; ++b) acc[a][b] = f4zero();

#pragma unroll
  for (int ks = 0; ks < 8; ++ks) {
    const int kb = ks * 32 + g * 8;
    bf16x8 af[4], bfr[4];
#pragma unroll
    for (int mf = 0; mf < 4; ++mf) {
      const int r = mf * 16 + lr;
      const int byt = (r * 512 + kb * 2) ^ ((r & 7) << 4);
      af[mf] = *(const bf16x8*)((const char*)t_lds + byt);
    }
#pragma unroll
    for (int nf = 0; nf < 4; ++nf) {
      const int col = w * 64 + nf * 16 + lr;
      bfr[nf] = *(const bf16x8*)(m2t + (size_t)col * 256 + kb);
    }
#pragma unroll
    for (int mf = 0; mf < 4; ++mf)
#pragma unroll
      for (int nf = 0; nf < 4; ++nf)
        acc[mf][nf] = MFMA(af[mf], bfr[nf], acc[mf][nf]);
  }

  __syncthreads();  // all stage-2 ds_reads done block-wide before overwrite

  // ---- epilogue 2: msg = ssp(acc+b2)*C * h1[src] -> t_lds (bf16)
  // swizzle: byte ^= ((er>>2)&3)<<5  (per-wave: g<<5 -> conflict-free writes)
#pragma unroll
  for (int nf = 0; nf < 4; ++nf) {
    const int col = w * 64 + nf * 16 + lr;
    const float bs = m2b[col];
#pragma unroll
    for (int mf = 0; mf < 4; ++mf) {
#pragma unroll
      for (int i = 0; i < 4; ++i) {
        const int er = mf * 16 + g * 4 + i;
        const float wf = sspf(acc[mf][nf][i] + bs) * Cs[er];
        const float xj = bf2f(h1[(size_t)s_src[er] * 256 + col]);
        const int byt = er * 512 + ((col * 2) ^ (((er >> 2) & 3) << 5));
        *(unsigned short*)((char*)t_lds + byt) = f2bf(xj * wf);
      }
    }
  }
  __syncthreads();

  // ---- segmented column reduce: thread tid owns column tid
  float sum = 0.0f;
#pragma unroll 8
  for (int r = 0; r < 64; ++r) {
    const int byt = r * 512 + ((tid * 2) ^ (((r >> 2) & 3) << 5));
    sum += bf2f(*(const unsigned short*)((const char*)t_lds + byt));
    const int d = s_dst[r];
    const bool flush = (r == 63) || (s_dst[r + 1] != d);   // uniform branch
    if (flush) {
      atomicAdd(agg + (size_t)d * 256 + tid, sum);
      sum = 0.0f;
    }
  }
}

// ---------------------------------------------------------------------------
// Transpose + downcast weights (unchanged)
// ---------------------------------------------------------------------------
__global__ __launch_bounds__(256) void prep_weights(
    const float* __restrict__ aw, const float* __restrict__ m1,
    const float* __restrict__ m2, const float* __restrict__ o1,
    const float* __restrict__ o2,
    unsigned short* __restrict__ awt, unsigned short* __restrict__ m1t,
    unsigned short* __restrict__ m2t, unsigned short* __restrict__ o1t,
    unsigned short* __restrict__ o2t)
{
  const int i = (int)blockIdx.x * 256 + (int)threadIdx.x;
  const int c = i >> 8, k = i & 255;
  const int src = k * 256 + c;
  awt[i] = f2bf(aw[src]);
  m2t[i] = f2bf(m2[src]);
  o1t[i] = f2bf(o1[src]);
  o2t[i] = f2bf(o2[src]);
  if (k < 64) m1t[c * 64 + k] = (k < 50) ? f2bf(m1[k * 256 + c]) : (unsigned short)0;
}

extern "C" void kernel_launch(void* const* d_in, const int* in_sizes, int n_in,
                              void* d_out, int out_size, void* d_ws, size_t ws_size,
                              hipStream_t stream)
{
  const float* h    = (const float*)d_in[0];
  const int*   eidx = (const int*)d_in[1];
  const float* ew   = (const float*)d_in[2];
  const float* ea   = (const float*)d_in[3];
  const float* awW  = (const float*)d_in[4];
  const float* awb  = (const float*)d_in[5];
  const float* m1W  = (const float*)d_in[6];
  const float* m1b  = (const float*)d_in[7];
  const float* m2W  = (const float*)d_in[8];
  const float* m2b  = (const float*)d_in[9];
  const float* o1W  = (const float*)d_in[10];
  const float* o1b  = (const float*)d_in[11];
  const float* o2W  = (const float*)d_in[12];
  const float* o2b  = (const float*)d_in[13];

  // ws layout (~81 MB):
  //   h1 bf16 [N,256] (reused for 'o') | agg f32 [N,256] | bf16 weights |
  //   cnt int[N] | cursor int[N] | perm int[E]
  char* ws = (char*)d_ws;
  unsigned short* h1  = (unsigned short*)ws;
  float*          agg = (float*)(ws + 25600000);
  char* wbase = ws + 25600000 + 51200000;
  unsigned short* awt = (unsigned short*)wbase;
  unsigned short* m2t = awt + 65536;
  unsigned short* o1t = m2t + 65536;
  unsigned short* o2t = o1t + 65536;
  unsigned short* m1t = o2t + 65536;            // [256][64]
  int* cnt    = (int*)(wbase + 4 * 131072 + 32768);
  int* cursor = cnt + N_NODES;
  int* perm   = cursor + N_NODES;

  hipMemsetAsync(agg, 0, (size_t)N_NODES * 256 * 4, stream);
  hipMemsetAsync(cnt, 0, (size_t)N_NODES * 4, stream);

  prep_weights<<<256, 256, 0, stream>>>(awW, m1W, m2W, o1W, o2W,
                                        awt, m1t, m2t, o1t, o2t);
  // counting sort by dst
  hist_dst<<<N_EDGES / 256, 256, 0, stream>>>(eidx, cnt);
  scan_cnt<<<1, 1024, 0, stream>>>(cnt, cursor);
  scatter_perm<<<N_EDGES / 256, 256, 0, stream>>>(eidx, cursor, perm);

  // h1 = h @ aw_W + aw_b
  gemm_k256<1, 0, 0><<<(N_NODES + 63) / 64, 256, 0, stream>>>(h, awt, awb, h1, N_NODES);
  // edge MLP + CFConv with segmented reduce
  edge_fused<<<N_EDGES / 64, 256, 0, stream>>>(ea, ew, eidx, perm,
                                               m1t, m1b, m2t, m2b, h1, agg);
  // o = ssp(agg @ o1_W + o1_b)   (into h1's buffer)
  gemm_k256<1, 1, 0><<<(N_NODES + 63) / 64, 256, 0, stream>>>(agg, o1t, o1b, h1, N_NODES);
  // out = o @ o2_W + o2_b
  gemm_k256<0, 0, 1><<<(N_NODES + 63) / 64, 256, 0, stream>>>(h1, o2t, o2b, d_out, N_NODES);
}

// Round 3
// 1249.441 us; speedup vs baseline: 1.1228x; 1.1161x over previous
//
#include <hip/hip_runtime.h>

#define N_NODES 50000
#define N_EDGES 800000

typedef __attribute__((ext_vector_type(8))) short bf16x8;
typedef __attribute__((ext_vector_type(4))) float f32x4;
typedef __attribute__((ext_vector_type(2))) float f32x2;

__device__ __forceinline__ float bf2f(unsigned short u) {
  union { unsigned int u; float f; } c; c.u = ((unsigned int)u) << 16; return c.f;
}
__device__ __forceinline__ unsigned short f2bf(float f) {
  union { float f; unsigned int u; } c; c.f = f;
  unsigned int r = c.u + 0x7FFFu + ((c.u >> 16) & 1u);  // RNE
  return (unsigned short)(r >> 16);
}
__device__ __forceinline__ float sspf(float x) {
  return fmaxf(x, 0.0f) + __logf(1.0f + __expf(-fabsf(x))) - 0.69314718055994531f;
}
__device__ __forceinline__ f32x4 MFMA(bf16x8 a, bf16x8 b, f32x4 c) {
  return __builtin_amdgcn_mfma_f32_16x16x32_bf16(a, b, c, 0, 0, 0);
}
__device__ __forceinline__ f32x4 f4zero() { f32x4 z = {0.f, 0.f, 0.f, 0.f}; return z; }

__device__ __forceinline__ bf16x8 cvt8(const float* __restrict__ p) {
  f32x4 x0 = *(const f32x4*)p;
  f32x4 x1 = *(const f32x4*)(p + 4);
  bf16x8 t;
  t[0] = (short)f2bf(x0[0]); t[1] = (short)f2bf(x0[1]);
  t[2] = (short)f2bf(x0[2]); t[3] = (short)f2bf(x0[3]);
  t[4] = (short)f2bf(x1[0]); t[5] = (short)f2bf(x1[1]);
  t[6] = (short)f2bf(x1[2]); t[7] = (short)f2bf(x1[3]);
  return t;
}

// ---------------------------------------------------------------------------
// Generic GEMM: Out[M,256] = act(A[M,256] @ W[256,256] + bias)   (unchanged)
// ---------------------------------------------------------------------------
template<int ADT, int ACT, int ODT>
__global__ __launch_bounds__(256) void gemm_k256(
    const void* __restrict__ Av, const unsigned short* __restrict__ Wt,
    const float* __restrict__ bias, void* __restrict__ Outv, int M)
{
  const int m0  = (int)blockIdx.x * 64;
  const int tid = (int)threadIdx.x;
  const int w   = tid >> 6;
  const int l   = tid & 63;
  const int lr  = l & 15;
  const int g   = l >> 4;

  f32x4 acc[4][4];
#pragma unroll
  for (int a = 0; a < 4; ++a)
#pragma unroll
    for (int b = 0; b < 4; ++b) acc[a][b] = f4zero();

#pragma unroll
  for (int ks = 0; ks < 8; ++ks) {
    const int kb = ks * 32 + g * 8;
    bf16x8 af[4], bfr[4];
#pragma unroll
    for (int mf = 0; mf < 4; ++mf) {
      int row = m0 + mf * 16 + lr;
      if (row >= M) row = M - 1;
      if (ADT == 0)
        af[mf] = *(const bf16x8*)((const unsigned short*)Av + (size_t)row * 256 + kb);
      else
        af[mf] = cvt8((const float*)Av + (size_t)row * 256 + kb);
    }
#pragma unroll
    for (int nf = 0; nf < 4; ++nf) {
      const int col = w * 64 + nf * 16 + lr;
      bfr[nf] = *(const bf16x8*)(Wt + (size_t)col * 256 + kb);
    }
#pragma unroll
    for (int mf = 0; mf < 4; ++mf)
#pragma unroll
      for (int nf = 0; nf < 4; ++nf)
        acc[mf][nf] = MFMA(af[mf], bfr[nf], acc[mf][nf]);
  }

#pragma unroll
  for (int nf = 0; nf < 4; ++nf) {
    const int col = w * 64 + nf * 16 + lr;
    const float bs = bias[col];
#pragma unroll
    for (int mf = 0; mf < 4; ++mf) {
#pragma unroll
      for (int i = 0; i < 4; ++i) {
        const int row = m0 + mf * 16 + g * 4 + i;
        if (row < M) {
          float x = acc[mf][nf][i] + bs;
          if (ACT) x = sspf(x);
          if (ODT == 0)
            ((unsigned short*)Outv)[(size_t)row * 256 + col] = f2bf(x);
          else
            ((float*)Outv)[(size_t)row * 256 + col] = x;
        }
      }
    }
  }
}

// ---------------------------------------------------------------------------
// Counting sort of edges by dst + sorted-order edge metadata.
// ---------------------------------------------------------------------------
__global__ __launch_bounds__(256) void hist_dst(const int* __restrict__ eidx,
                                                int* __restrict__ cnt)
{
  const int e = (int)blockIdx.x * 256 + (int)threadIdx.x;
  atomicAdd(&cnt[eidx[N_EDGES + e]], 1);
}

__global__ __launch_bounds__(1024) void scan_cnt(const int* __restrict__ cnt,
                                                 int* __restrict__ cursor)
{
  __shared__ int part[1024];
  const int t = (int)threadIdx.x;
  const int base = t * 49;
  int s = 0;
#pragma unroll 7
  for (int j = 0; j < 49; ++j) {
    const int idx = base + j;
    if (idx < N_NODES) s += cnt[idx];
  }
  part[t] = s;
  __syncthreads();
  for (int off = 1; off < 1024; off <<= 1) {
    int v = 0;
    if (t >= off) v = part[t - off];
    __syncthreads();
    part[t] += v;
    __syncthreads();
  }
  int run = (t == 0) ? 0 : part[t - 1];
#pragma unroll 7
  for (int j = 0; j < 49; ++j) {
    const int idx = base + j;
    if (idx < N_NODES) { cursor[idx] = run; run += cnt[idx]; }
  }
}

// also emits per-sorted-edge metadata (Cf/srcs/dsts) when pointers non-null
__global__ __launch_bounds__(256) void scatter_perm(
    const int* __restrict__ eidx, const float* __restrict__ ew,
    int* __restrict__ cursor, int* __restrict__ perm,
    float* __restrict__ Cf, int* __restrict__ srcs, int* __restrict__ dsts)
{
  const int e = (int)blockIdx.x * 256 + (int)threadIdx.x;
  const int d = eidx[N_EDGES + e];
  const int pos = atomicAdd(&cursor[d], 1);
  perm[pos] = e;
  if (Cf) {
    Cf[pos]   = 0.5f * (__cosf(ew[e] * 0.31415926535897931f) + 1.0f);
    srcs[pos] = eidx[e];
    dsts[pos] = d;
  }
}

// eattr_s[i][64] bf16 = eattr[perm[i]][k] (k<50), 0-padded. 8 lanes/edge.
__global__ __launch_bounds__(256) void prep_eattr(
    const float* __restrict__ ea, const int* __restrict__ perm,
    unsigned short* __restrict__ out)
{
  const int t = (int)blockIdx.x * 256 + (int)threadIdx.x;
  const int i = t >> 3, j = t & 7;
  const int p = perm[i];
  const float* ap = ea + (size_t)p * 50 + j * 8;
  bf16x8 v;
  if (j < 6) {
    f32x2 a0 = *(const f32x2*)(ap);
    f32x2 a1 = *(const f32x2*)(ap + 2);
    f32x2 a2 = *(const f32x2*)(ap + 4);
    f32x2 a3 = *(const f32x2*)(ap + 6);
    v[0] = (short)f2bf(a0[0]); v[1] = (short)f2bf(a0[1]);
    v[2] = (short)f2bf(a1[0]); v[3] = (short)f2bf(a1[1]);
    v[4] = (short)f2bf(a2[0]); v[5] = (short)f2bf(a2[1]);
    v[6] = (short)f2bf(a3[0]); v[7] = (short)f2bf(a3[1]);
  } else if (j == 6) {
    f32x2 a0 = *(const f32x2*)(ap);
    v[0] = (short)f2bf(a0[0]); v[1] = (short)f2bf(a0[1]);
    v[2] = 0; v[3] = 0; v[4] = 0; v[5] = 0; v[6] = 0; v[7] = 0;
  } else {
    v[0] = 0; v[1] = 0; v[2] = 0; v[3] = 0; v[4] = 0; v[5] = 0; v[6] = 0; v[7] = 0;
  }
  *(bf16x8*)(out + (size_t)i * 64 + j * 8) = v;
}

// ---------------------------------------------------------------------------
// Fused edge pipeline over dst-sorted edges, 64/block.
// PREP=1: coalesced bf16 eattr_s + precomputed Cf/srcs/dsts.
// PREP=0: fallback (in-kernel permuted gather), if ws too small.
// Reduce: Wf in LDS; gather h1 with lane=column (coalesced 512B rows),
// thread handles a column pair, rows split 2x32.
// ---------------------------------------------------------------------------
template<int PREP>
__global__ __launch_bounds__(256) void edge_fused(
    const float* __restrict__ eattr, const unsigned short* __restrict__ eattr_s,
    const float* __restrict__ ew, const int* __restrict__ eidx,
    const int* __restrict__ perm, const float* __restrict__ Cf,
    const int* __restrict__ srcs, const int* __restrict__ dsts,
    const unsigned short* __restrict__ m1t, const float* __restrict__ m1b,
    const unsigned short* __restrict__ m2t, const float* __restrict__ m2b,
    const unsigned short* __restrict__ h1, float* __restrict__ agg)
{
  __shared__ unsigned short t_lds[64 * 256];  // 32 KiB; t, then Wf
  __shared__ float Cs[64];
  __shared__ int s_src[64], s_dst[64], s_perm[64];

  const int e0  = (int)blockIdx.x * 64;
  const int tid = (int)threadIdx.x;
  if (tid < 64) {
    if (PREP) {
      Cs[tid]    = Cf[e0 + tid];
      s_src[tid] = srcs[e0 + tid];
      s_dst[tid] = dsts[e0 + tid];
    } else {
      const int p = perm[e0 + tid];
      s_perm[tid] = p;
      Cs[tid]     = 0.5f * (__cosf(ew[p] * 0.31415926535897931f) + 1.0f);
      s_src[tid]  = eidx[p];
      s_dst[tid]  = eidx[N_EDGES + p];
    }
  }
  __syncthreads();

  const int w = tid >> 6, l = tid & 63, lr = l & 15, g = l >> 4;

  f32x4 acc[4][4];
#pragma unroll
  for (int a = 0; a < 4; ++a)
#pragma unroll
    for (int b = 0; b < 4; ++b) acc[a][b] = f4zero();

  // ---- stage 1: K=50 padded to 64 (m1t zero-padded)
#pragma unroll
  for (int ks = 0; ks < 2; ++ks) {
    const int kb = ks * 32 + g * 8;
    bf16x8 af[4], bfr[4];
#pragma unroll
    for (int mf = 0; mf < 4; ++mf) {
      if (PREP) {
        af[mf] = *(const bf16x8*)(eattr_s + (size_t)(e0 + mf * 16 + lr) * 64 + kb);
      } else {
        const int pr = s_perm[mf * 16 + lr];
        const float* ap = eattr + (size_t)pr * 50 + kb;
        bf16x8 t;
        if (kb + 8 <= 50) {
          f32x2 x0 = *(const f32x2*)(ap);
          f32x2 x1 = *(const f32x2*)(ap + 2);
          f32x2 x2 = *(const f32x2*)(ap + 4);
          f32x2 x3 = *(const f32x2*)(ap + 6);
          t[0] = (short)f2bf(x0[0]); t[1] = (short)f2bf(x0[1]);
          t[2] = (short)f2bf(x1[0]); t[3] = (short)f2bf(x1[1]);
          t[4] = (short)f2bf(x2[0]); t[5] = (short)f2bf(x2[1]);
          t[6] = (short)f2bf(x3[0]); t[7] = (short)f2bf(x3[1]);
        } else {
#pragma unroll
          for (int j = 0; j < 8; ++j)
            t[j] = (kb + j < 50) ? (short)f2bf(ap[j]) : (short)0;
        }
        af[mf] = t;
      }
    }
#pragma unroll
    for (int nf = 0; nf < 4; ++nf) {
      const int col = w * 64 + nf * 16 + lr;
      bfr[nf] = *(const bf16x8*)(m1t + col * 64 + kb);
    }
#pragma unroll
    for (int mf = 0; mf < 4; ++mf)
#pragma unroll
      for (int nf = 0; nf < 4; ++nf)
        acc[mf][nf] = MFMA(af[mf], bfr[nf], acc[mf][nf]);
  }

  // ---- epilogue 1: t = ssp(.) -> t_lds (bf16, byte ^= (row&7)<<4)
#pragma unroll
  for (int nf = 0; nf < 4; ++nf) {
    const int col = w * 64 + nf * 16 + lr;
    const float bs = m1b[col];
#pragma unroll
    for (int mf = 0; mf < 4; ++mf)
#pragma unroll
      for (int i = 0; i < 4; ++i) {
        const int r = mf * 16 + g * 4 + i;
        const float x = sspf(acc[mf][nf][i] + bs);
        const int byt = (r * 512 + col * 2) ^ ((r & 7) << 4);
        *(unsigned short*)((char*)t_lds + byt) = f2bf(x);
      }
  }
  __syncthreads();

  // ---- stage 2: K=256
#pragma unroll
  for (int a = 0; a < 4; ++a)
#pragma unroll
    for (int b = 0; b < 4; ++b) acc[a][b] = f4zero();

#pragma unroll
  for (int ks = 0; ks < 8; ++ks) {
    const int kb = ks * 32 + g * 8;
    bf16x8 af[4], bfr[4];
#pragma unroll
    for (int mf = 0; mf < 4; ++mf) {
      const int r = mf * 16 + lr;
      const int byt = (r * 512 + kb * 2) ^ ((r & 7) << 4);
      af[mf] = *(const bf16x8*)((const char*)t_lds + byt);
    }
#pragma unroll
    for (int nf = 0; nf < 4; ++nf) {
      const int col = w * 64 + nf * 16 + lr;
      bfr[nf] = *(const bf16x8*)(m2t + (size_t)col * 256 + kb);
    }
#pragma unroll
    for (int mf = 0; mf < 4; ++mf)
#pragma unroll
      for (int nf = 0; nf < 4; ++nf)
        acc[mf][nf] = MFMA(af[mf], bfr[nf], acc[mf][nf]);
  }

  __syncthreads();  // stage-2 reads complete block-wide before overwrite

  // ---- epilogue 2: Wf = ssp(acc+b2)*C -> t_lds (same swizzle; NO gather)
#pragma unroll
  for (int nf = 0; nf < 4; ++nf) {
    const int col = w * 64 + nf * 16 + lr;
    const float bs = m2b[col];
#pragma unroll
    for (int mf = 0; mf < 4; ++mf) {
#pragma unroll
      for (int i = 0; i < 4; ++i) {
        const int er = mf * 16 + g * 4 + i;
        const float wf = sspf(acc[mf][nf][i] + bs) * Cs[er];
        const int byt = (er * 512 + col * 2) ^ ((er & 7) << 4);
        *(unsigned short*)((char*)t_lds + byt) = f2bf(wf);
      }
    }
  }
  __syncthreads();

  // ---- segmented reduce: thread owns column pair (2cp,2cp+1),
  // rows split 2x32 across thread halves; h1 gather coalesced by column.
  {
    const int half  = tid >> 7;          // 0: rows 0..31, 1: rows 32..63
    const int cp    = tid & 127;
    const int col2  = cp * 2;
    const int rbase = half * 32;
    float s0 = 0.0f, s1 = 0.0f;
#pragma unroll 8
    for (int rr = 0; rr < 32; ++rr) {
      const int r = rbase + rr;
      const int byt = (r * 512 + col2 * 2) ^ ((r & 7) << 4);
      const unsigned int wfp = *(const unsigned int*)((const char*)t_lds + byt);
      const unsigned int xjp =
          *(const unsigned int*)(h1 + (size_t)s_src[r] * 256 + col2);
      s0 += bf2f((unsigned short)(wfp & 0xffff)) * bf2f((unsigned short)(xjp & 0xffff));
      s1 += bf2f((unsigned short)(wfp >> 16)) * bf2f((unsigned short)(xjp >> 16));
      const int d = s_dst[r];
      const bool flush = (rr == 31) || (s_dst[r + 1] != d);  // uniform/wave
      if (flush) {
        float* ap = agg + (size_t)d * 256 + col2;
        atomicAdd(ap, s0);
        atomicAdd(ap + 1, s1);
        s0 = 0.0f; s1 = 0.0f;
      }
    }
  }
}

// ---------------------------------------------------------------------------
// Transpose + downcast weights (unchanged)
// ---------------------------------------------------------------------------
__global__ __launch_bounds__(256) void prep_weights(
    const float* __restrict__ aw, const float* __restrict__ m1,
    const float* __restrict__ m2, const float* __restrict__ o1,
    const float* __restrict__ o2,
    unsigned short* __restrict__ awt, unsigned short* __restrict__ m1t,
    unsigned short* __restrict__ m2t, unsigned short* __restrict__ o1t,
    unsigned short* __restrict__ o2t)
{
  const int i = (int)blockIdx.x * 256 + (int)threadIdx.x;
  const int c = i >> 8, k = i & 255;
  const int src = k * 256 + c;
  awt[i] = f2bf(aw[src]);
  m2t[i] = f2bf(m2[src]);
  o1t[i] = f2bf(o1[src]);
  o2t[i] = f2bf(o2[src]);
  if (k < 64) m1t[c * 64 + k] = (k < 50) ? f2bf(m1[k * 256 + c]) : (unsigned short)0;
}

extern "C" void kernel_launch(void* const* d_in, const int* in_sizes, int n_in,
                              void* d_out, int out_size, void* d_ws, size_t ws_size,
                              hipStream_t stream)
{
  const float* h    = (const float*)d_in[0];
  const int*   eidx = (const int*)d_in[1];
  const float* ew   = (const float*)d_in[2];
  const float* ea   = (const float*)d_in[3];
  const float* awW  = (const float*)d_in[4];
  const float* awb  = (const float*)d_in[5];
  const float* m1W  = (const float*)d_in[6];
  const float* m1b  = (const float*)d_in[7];
  const float* m2W  = (const float*)d_in[8];
  const float* m2b  = (const float*)d_in[9];
  const float* o1W  = (const float*)d_in[10];
  const float* o1b  = (const float*)d_in[11];
  const float* o2W  = (const float*)d_in[12];
  const float* o2b  = (const float*)d_in[13];

  char* ws = (char*)d_ws;
  unsigned short* h1  = (unsigned short*)ws;                  // 25,600,000 B
  float*          agg = (float*)(ws + 25600000);              // 51,200,000 B
  char* wbase = ws + 25600000 + 51200000;                     // 76,800,000
  unsigned short* awt = (unsigned short*)wbase;               // 131072 B
  unsigned short* m2t = awt + 65536;                          // 131072 B
  unsigned short* o1t = m2t + 65536;                          // 131072 B
  unsigned short* o2t = o1t + 65536;                          // 131072 B
  unsigned short* m1t = o2t + 65536;                          // 32768 B
  char* p0 = wbase + 4 * 131072 + 32768;                      // 77,357,056
  int* cnt    = (int*)p0;                                     // 200,000 B
  int* cursor = cnt + N_NODES;                                // 200,000 B
  int* perm   = cursor + N_NODES;                             // 3,200,000 B
  char* p1 = p0 + 400000 + 3200000;                           // 80,957,056
  float* Cf   = (float*)p1;                                   // 3,200,000 B
  int*   srcs = (int*)(p1 + 3200000);                         // 3,200,000 B
  int*   dsts = (int*)(p1 + 6400000);                         // 3,200,000 B
  unsigned short* eattr_s = (unsigned short*)(p1 + 9600000);  // 102,400,000 B
  const size_t need_prep = 80957056 + 9600000 + 102400000;    // ~193 MB

  const bool PREP = (ws_size >= need_prep);

  hipMemsetAsync(agg, 0, (size_t)N_NODES * 256 * 4, stream);
  hipMemsetAsync(cnt, 0, (size_t)N_NODES * 4, stream);

  prep_weights<<<256, 256, 0, stream>>>(awW, m1W, m2W, o1W, o2W,
                                        awt, m1t, m2t, o1t, o2t);
  hist_dst<<<N_EDGES / 256, 256, 0, stream>>>(eidx, cnt);
  scan_cnt<<<1, 1024, 0, stream>>>(cnt, cursor);
  scatter_perm<<<N_EDGES / 256, 256, 0, stream>>>(
      eidx, ew, cursor, perm,
      PREP ? Cf : (float*)nullptr, PREP ? srcs : (int*)nullptr,
      PREP ? dsts : (int*)nullptr);
  if (PREP)
    prep_eattr<<<N_EDGES * 8 / 256, 256, 0, stream>>>(ea, perm, eattr_s);

  // h1 = h @ aw_W + aw_b
  gemm_k256<1, 0, 0><<<(N_NODES + 63) / 64, 256, 0, stream>>>(h, awt, awb, h1, N_NODES);

  if (PREP)
    edge_fused<1><<<N_EDGES / 64, 256, 0, stream>>>(
        ea, eattr_s, ew, eidx, perm, Cf, srcs, dsts,
        m1t, m1b, m2t, m2b, h1, agg);
  else
    edge_fused<0><<<N_EDGES / 64, 256, 0, stream>>>(
        ea, eattr_s, ew, eidx, perm, Cf, srcs, dsts,
        m1t, m1b, m2t, m2b, h1, agg);

  // o = ssp(agg @ o1_W + o1_b)   (into h1's buffer)
  gemm_k256<1, 1, 0><<<(N_NODES + 63) / 64, 256, 0, stream>>>(agg, o1t, o1b, h1, N_NODES);
  // out = o @ o2_W + o2_b
  gemm_k256<0, 0, 1><<<(N_NODES + 63) / 64, 256, 0, stream>>>(h1, o2t, o2b, d_out, N_NODES);
}